// Round 1
// baseline (983.739 us; speedup 1.0000x reference)
//
#include <hip/hip_runtime.h>
#include <stdint.h>

// GRU-D forward, MI355X. Shapes: B=512, steps S=128 (feature axis), T=128, H=256.
// Pipeline: pack_w (repack weights bf16) -> prep (imputation, build Cin)
//   -> u_gemm (precompute all h-independent preactivations U, bf16, 128MB)
//   -> recur (32 persistent blocks x 16 batch rows, 128 sequential steps, MFMA)
//   -> bn_stats (BN+fc collapse to affine) -> fin (output dot).
// Workspace required: ~187 MB.

#define NSTEP 128
#define NT    128
#define NBAT  512
#define NH    256

typedef __attribute__((ext_vector_type(8))) short bf16x8;
typedef __attribute__((ext_vector_type(4))) float f32x4;

__device__ __forceinline__ float bf2f(unsigned short u) {
  union { unsigned int i; float f; } v; v.i = ((unsigned int)u) << 16; return v.f;
}
__device__ __forceinline__ unsigned short f2bf(float f) {
  union { float f; unsigned int i; } v; v.f = f;
  unsigned int x = v.i;
  return (unsigned short)((x + 0x7fffu + ((x >> 16) & 1u)) >> 16);  // RNE
}
__device__ __forceinline__ float sigm(float x) { return 1.f / (1.f + __expf(-x)); }

// ---------------------------------------------------------------------------
// pack_w: build bf16 weight layouts + bias vector + transposed X_mean.
//  Wpre  [1024][384]: rows 0:768 = gates(z,r,h): k 0:128 = W*x, k 128:256 = W*m,
//                     k 256:384 = 0;  rows 768:1024 = g: k 256:384 = Wgh.
//  Wzrh  [512][256]  : z,r h-recurrent cols.   Whh [256][256] : h-gate recurrent.
//  Bpre  [1024] fp32 : [bz|br|bh|bgh].         XmT [128][128]: X_mean transposed.
// ---------------------------------------------------------------------------
__global__ void pack_w(const float* __restrict__ Wz, const float* __restrict__ Wr,
                       const float* __restrict__ Wh, const float* __restrict__ Wgh,
                       const float* __restrict__ bz, const float* __restrict__ br,
                       const float* __restrict__ bh, const float* __restrict__ bgh,
                       const float* __restrict__ Xmean,
                       unsigned short* __restrict__ Wpre, unsigned short* __restrict__ Wzrh,
                       unsigned short* __restrict__ WhhP, float* __restrict__ Bpre,
                       float* __restrict__ XmT) {
  int id = blockIdx.x * 256 + threadIdx.x;
  if (id < 1024 * 384) {
    int j = id / 384, k = id % 384;
    float v = 0.f;
    if (j < 768) {
      const float* W = (j < 256) ? Wz : (j < 512) ? Wr : Wh;
      int jj = j & 255;
      if (k < 128)      v = W[jj * 512 + k];                // x segment
      else if (k < 256) v = W[jj * 512 + 384 + (k - 128)];  // m segment
    } else {
      int jj = j - 768;
      if (k >= 256) v = Wgh[jj * 128 + (k - 256)];          // d segment
    }
    Wpre[id] = f2bf(v);
    return;
  }
  int id2 = id - 1024 * 384;
  if (id2 < 512 * 256) {
    int j = id2 >> 8, i = id2 & 255;
    float v = (j < 256) ? Wz[j * 512 + 128 + i] : Wr[(j - 256) * 512 + 128 + i];
    Wzrh[id2] = f2bf(v);
    return;
  }
  int id3 = id2 - 512 * 256;
  if (id3 < 256 * 256) {
    int j = id3 >> 8, i = id3 & 255;
    WhhP[id3] = f2bf(Wh[j * 512 + 128 + i]);
    return;
  }
  int id4 = id3 - 256 * 256;
  if (id4 < 1024) {
    float v = (id4 < 256) ? bz[id4] : (id4 < 512) ? br[id4 - 256]
            : (id4 < 768) ? bh[id4 - 512] : bgh[id4 - 768];
    Bpre[id4] = v;
    return;
  }
  int id5 = id4 - 1024;
  if (id5 < 128 * 128) {
    int t = id5 >> 7, s = id5 & 127;
    XmT[t * 128 + s] = Xmean[s * 128 + t];
  }
}

// ---------------------------------------------------------------------------
// prep: imputation + build Cin[s][b][k] bf16, k: 0:128=x_tilde, 128:256=m, 256:384=d.
// block = (b, t-chunk of 64), 128 threads (thread = s). Transpose via LDS.
// ---------------------------------------------------------------------------
__global__ __launch_bounds__(128) void prep(const float* __restrict__ X,
                                            const float* __restrict__ XmT,
                                            const float* __restrict__ Wgx,
                                            const float* __restrict__ bgx,
                                            unsigned short* __restrict__ Cin) {
  __shared__ unsigned short lx[64][132], lm[64][132], ldl[64][132];
  int b = blockIdx.x >> 1, tc = blockIdx.x & 1;
  int s = threadIdx.x;  // 0..127
  const float* Xb = X + (size_t)b * 384 * 128;
  for (int tt = 0; tt < 64; ++tt) {
    int t = tc * 64 + tt;
    float m = Xb[(3 * t + 0) * 128 + s];
    float x = Xb[(3 * t + 1) * 128 + s];
    float d = Xb[(3 * t + 2) * 128 + s];
    float wg = Wgx[t * 128 + t];   // diag (FilterLinear w/ identity)
    float bg = bgx[t];
    float dx = __expf(-fmaxf(d * wg + bg, 0.f));
    float xm = XmT[t * 128 + s];
    float xt = m * x + (1.f - m) * (dx * x + (1.f - dx) * xm);
    lx[tt][s]  = f2bf(xt);
    lm[tt][s]  = f2bf(m);
    ldl[tt][s] = f2bf(d);
  }
  __syncthreads();
  for (int s0 = 0; s0 < 128; s0 += 2) {
    int ss = s0 + (threadIdx.x >> 6);
    int t  = threadIdx.x & 63;
    size_t base = ((size_t)ss * NBAT + b) * 384;
    Cin[base +       tc * 64 + t] = lx[t][ss];
    Cin[base + 128 + tc * 64 + t] = lm[t][ss];
    Cin[base + 256 + tc * 64 + t] = ldl[t][ss];
  }
}

// ---------------------------------------------------------------------------
// u_gemm: U[s][bt][j][b16] bf16 = Cin @ Wpre^T + Bpre  (h-independent preacts).
// block: one s, 64 batch rows (4 m-tiles), 4 waves: waves 0-2 = gate rows
// (K 0:256), wave 3 = g rows (K 256:384). A staged in LDS; W streamed from L2.
// ---------------------------------------------------------------------------
__global__ __launch_bounds__(256) void u_gemm(const unsigned short* __restrict__ Cin,
                                              const unsigned short* __restrict__ Wpre,
                                              const float* __restrict__ Bpre,
                                              unsigned short* __restrict__ Upre) {
  __shared__ unsigned short Ash[64][392];  // 64 rows x 384 (+8 pad)
  int s  = blockIdx.x >> 3;
  int bc = blockIdx.x & 7;
  int b0 = bc * 64;
  {
    int r = threadIdx.x >> 2, part = threadIdx.x & 3;
    const uint4* src = (const uint4*)(Cin + ((size_t)s * NBAT + b0 + r) * 384);
    uint4* dst = (uint4*)&Ash[r][0];
#pragma unroll
    for (int q = 0; q < 12; ++q) dst[part + q * 4] = src[part + q * 4];
  }
  __syncthreads();
  int wid = threadIdx.x >> 6, lane = threadIdx.x & 63;
  int col = lane & 15, kq = lane >> 4;

  if (wid < 3) {  // gate rows, K = 0:256
    int jbase = wid * 256;
    bf16x8 af[4][8];
#pragma unroll
    for (int mt = 0; mt < 4; ++mt)
#pragma unroll
      for (int kt = 0; kt < 8; ++kt)
        af[mt][kt] = *(const bf16x8*)&Ash[mt * 16 + col][kt * 32 + kq * 8];
    for (int jt = 0; jt < 16; ++jt) {
      int j0 = jbase + jt * 16;
      const unsigned short* wrow = Wpre + (size_t)(j0 + col) * 384 + kq * 8;
      f32x4 C0 = {0,0,0,0}, C1 = {0,0,0,0}, C2 = {0,0,0,0}, C3 = {0,0,0,0};
#pragma unroll
      for (int kt = 0; kt < 8; ++kt) {
        bf16x8 bw = *(const bf16x8*)(wrow + kt * 32);
        C0 = __builtin_amdgcn_mfma_f32_16x16x32_bf16(af[0][kt], bw, C0, 0, 0, 0);
        C1 = __builtin_amdgcn_mfma_f32_16x16x32_bf16(af[1][kt], bw, C1, 0, 0, 0);
        C2 = __builtin_amdgcn_mfma_f32_16x16x32_bf16(af[2][kt], bw, C2, 0, 0, 0);
        C3 = __builtin_amdgcn_mfma_f32_16x16x32_bf16(af[3][kt], bw, C3, 0, 0, 0);
      }
      int j = j0 + col;
      float bias = Bpre[j];
      f32x4 Cs[4] = {C0, C1, C2, C3};
#pragma unroll
      for (int mt = 0; mt < 4; ++mt) {
        int bt = bc * 4 + mt;
        ushort4 o;
        o.x = f2bf(Cs[mt][0] + bias); o.y = f2bf(Cs[mt][1] + bias);
        o.z = f2bf(Cs[mt][2] + bias); o.w = f2bf(Cs[mt][3] + bias);
        *(ushort4*)(Upre + (((size_t)s * 32 + bt) * 1024 + j) * 16 + kq * 4) = o;
      }
    }
  } else {  // g rows (dh preact), K = 256:384
    bf16x8 af[4][4];
#pragma unroll
    for (int mt = 0; mt < 4; ++mt)
#pragma unroll
      for (int kt = 0; kt < 4; ++kt)
        af[mt][kt] = *(const bf16x8*)&Ash[mt * 16 + col][256 + kt * 32 + kq * 8];
    for (int jt = 0; jt < 16; ++jt) {
      int j0 = 768 + jt * 16;
      const unsigned short* wrow = Wpre + (size_t)(j0 + col) * 384 + 256 + kq * 8;
      f32x4 C0 = {0,0,0,0}, C1 = {0,0,0,0}, C2 = {0,0,0,0}, C3 = {0,0,0,0};
#pragma unroll
      for (int kt = 0; kt < 4; ++kt) {
        bf16x8 bw = *(const bf16x8*)(wrow + kt * 32);
        C0 = __builtin_amdgcn_mfma_f32_16x16x32_bf16(af[0][kt], bw, C0, 0, 0, 0);
        C1 = __builtin_amdgcn_mfma_f32_16x16x32_bf16(af[1][kt], bw, C1, 0, 0, 0);
        C2 = __builtin_amdgcn_mfma_f32_16x16x32_bf16(af[2][kt], bw, C2, 0, 0, 0);
        C3 = __builtin_amdgcn_mfma_f32_16x16x32_bf16(af[3][kt], bw, C3, 0, 0, 0);
      }
      int j = j0 + col;
      float bias = Bpre[j];
      f32x4 Cs[4] = {C0, C1, C2, C3};
#pragma unroll
      for (int mt = 0; mt < 4; ++mt) {
        int bt = bc * 4 + mt;
        ushort4 o;
        o.x = f2bf(Cs[mt][0] + bias); o.y = f2bf(Cs[mt][1] + bias);
        o.z = f2bf(Cs[mt][2] + bias); o.w = f2bf(Cs[mt][3] + bias);
        *(ushort4*)(Upre + (((size_t)s * 32 + bt) * 1024 + j) * 16 + kq * 4) = o;
      }
    }
  }
}

// ---------------------------------------------------------------------------
// recur: persistent recurrence. 32 blocks x 512 threads (8 waves), 16 batch
// rows/block. h state fp32 in LDS; per step: decay -> GEMM1 (z,r; 512 rows
// split over 8 waves) -> GEMM2 (ht; 256 rows) -> update. Weights from L2.
// ---------------------------------------------------------------------------
__global__ __launch_bounds__(512) void recur(const unsigned short* __restrict__ Upre,
                                             const unsigned short* __restrict__ Wzrh,
                                             const unsigned short* __restrict__ WhhP,
                                             float* __restrict__ hT) {
  __shared__ float hf[16][260];           // h (then decayed h) fp32, [b][i]
  __shared__ float zf[16][260];           // z fp32, [b][j]
  __shared__ unsigned short hb[16][264];  // decayed h bf16, [b][i]
  __shared__ unsigned short qb[16][264];  // q = r*h bf16, [b][i]
  int bt = blockIdx.x;
  int tid = threadIdx.x;
  for (int i = tid; i < 16 * 260; i += 512) ((float*)hf)[i] = 0.f;  // h0 = 0
  __syncthreads();
  int wid = tid >> 6, lane = tid & 63;
  int col = lane & 15, kq = lane >> 4;
  int pb = tid & 15, pi0 = tid >> 4;

  for (int s = 0; s < NSTEP; ++s) {
    const unsigned short* Ub = Upre + ((size_t)s * 32 + bt) * (1024 * 16);
    // phase 0: hidden decay, repack bf16
#pragma unroll
    for (int r = 0; r < 8; ++r) {
      int i = pi0 + r * 32;
      float ug = bf2f(Ub[(768 + i) * 16 + pb]);
      float dh = __expf(-fmaxf(ug, 0.f));
      float hv = hf[pb][i] * dh;
      hf[pb][i] = hv;
      hb[pb][i] = f2bf(hv);
    }
    __syncthreads();
    // GEMM1: z (waves 0-3) and r->q (waves 4-7), 64 rows/wave
    bf16x8 bfr[8];
#pragma unroll
    for (int kt = 0; kt < 8; ++kt)
      bfr[kt] = *(const bf16x8*)&hb[col][kt * 32 + kq * 8];
    int jbase = wid * 64;
#pragma unroll
    for (int mt = 0; mt < 4; ++mt) {
      int j0 = jbase + mt * 16;
      const unsigned short* arow = Wzrh + (size_t)(j0 + col) * 256 + kq * 8;
      f32x4 C = {0,0,0,0};
#pragma unroll
      for (int kt = 0; kt < 8; ++kt) {
        bf16x8 a = *(const bf16x8*)(arow + kt * 32);
        C = __builtin_amdgcn_mfma_f32_16x16x32_bf16(a, bfr[kt], C, 0, 0, 0);
      }
      int jr = j0 + kq * 4;
      if (wid < 4) {
        float4 z;
        z.x = sigm(C[0] + bf2f(Ub[(jr + 0) * 16 + col]));
        z.y = sigm(C[1] + bf2f(Ub[(jr + 1) * 16 + col]));
        z.z = sigm(C[2] + bf2f(Ub[(jr + 2) * 16 + col]));
        z.w = sigm(C[3] + bf2f(Ub[(jr + 3) * 16 + col]));
        *(float4*)&zf[col][jr] = z;
      } else {
        int i0 = jr - 256;
        float4 hv = *(const float4*)&hf[col][i0];
        ushort4 q;
        q.x = f2bf(hv.x * sigm(C[0] + bf2f(Ub[(jr + 0) * 16 + col])));
        q.y = f2bf(hv.y * sigm(C[1] + bf2f(Ub[(jr + 1) * 16 + col])));
        q.z = f2bf(hv.z * sigm(C[2] + bf2f(Ub[(jr + 2) * 16 + col])));
        q.w = f2bf(hv.w * sigm(C[3] + bf2f(Ub[(jr + 3) * 16 + col])));
        *(ushort4*)&qb[col][i0] = q;
      }
    }
    __syncthreads();
    // GEMM2: ht + state update, 32 rows/wave
    bf16x8 bq[8];
#pragma unroll
    for (int kt = 0; kt < 8; ++kt)
      bq[kt] = *(const bf16x8*)&qb[col][kt * 32 + kq * 8];
#pragma unroll
    for (int mt = 0; mt < 2; ++mt) {
      int j0 = wid * 32 + mt * 16;
      const unsigned short* arow = WhhP + (size_t)(j0 + col) * 256 + kq * 8;
      f32x4 C = {0,0,0,0};
#pragma unroll
      for (int kt = 0; kt < 8; ++kt) {
        bf16x8 a = *(const bf16x8*)(arow + kt * 32);
        C = __builtin_amdgcn_mfma_f32_16x16x32_bf16(a, bq[kt], C, 0, 0, 0);
      }
      int jr = j0 + kq * 4;
      float p0 = C[0] + bf2f(Ub[(512 + jr + 0) * 16 + col]);
      float p1 = C[1] + bf2f(Ub[(512 + jr + 1) * 16 + col]);
      float p2 = C[2] + bf2f(Ub[(512 + jr + 2) * 16 + col]);
      float p3 = C[3] + bf2f(Ub[(512 + jr + 3) * 16 + col]);
      float4 z  = *(const float4*)&zf[col][jr];
      float4 hv = *(const float4*)&hf[col][jr];
      float4 hn;
      hn.x = (1.f - z.x) * hv.x + z.x * tanhf(p0);
      hn.y = (1.f - z.y) * hv.y + z.y * tanhf(p1);
      hn.z = (1.f - z.z) * hv.z + z.z * tanhf(p2);
      hn.w = (1.f - z.w) * hv.w + z.w * tanhf(p3);
      *(float4*)&hf[col][jr] = hn;
    }
    __syncthreads();
  }
  // write hT
  int bb = tid >> 5, j0 = (tid & 31) * 8;
  *(float4*)&hT[((size_t)bt * 16 + bb) * 256 + j0]     = *(const float4*)&hf[bb][j0];
  *(float4*)&hT[((size_t)bt * 16 + bb) * 256 + j0 + 4] = *(const float4*)&hf[bb][j0 + 4];
}

// ---------------------------------------------------------------------------
// bn_stats: BN(batch stats) + fc collapse to affine: out = hT @ a + c.
// ---------------------------------------------------------------------------
__global__ __launch_bounds__(256) void bn_stats(const float* __restrict__ hT,
                                                const float* __restrict__ gamma,
                                                const float* __restrict__ beta,
                                                const float* __restrict__ Wfc,
                                                const float* __restrict__ bfc,
                                                float* __restrict__ av) {
  int j = threadIdx.x;
  float sum = 0.f, sum2 = 0.f;
  for (int b = 0; b < NBAT; ++b) {
    float v = hT[(size_t)b * 256 + j];
    sum += v; sum2 += v * v;
  }
  float mu = sum * (1.f / NBAT);
  float var = sum2 * (1.f / NBAT) - mu * mu;
  float a = gamma[j] * Wfc[j] * rsqrtf(var + 1e-5f);
  av[j] = a;
  __shared__ float red[256];
  red[j] = beta[j] * Wfc[j] - a * mu;
  __syncthreads();
  for (int o = 128; o; o >>= 1) {
    if (j < o) red[j] += red[j + o];
    __syncthreads();
  }
  if (j == 0) av[256] = red[0] + bfc[0];
}

__global__ __launch_bounds__(64) void fin(const float* __restrict__ hT,
                                          const float* __restrict__ av,
                                          float* __restrict__ out) {
  int b = blockIdx.x, lane = threadIdx.x;
  float4 hv = *(const float4*)&hT[(size_t)b * 256 + lane * 4];
  float4 a  = *(const float4*)&av[lane * 4];
  float d = hv.x * a.x + hv.y * a.y + hv.z * a.z + hv.w * a.w;
  for (int o = 32; o; o >>= 1) d += __shfl_down(d, o);
  if (lane == 0) out[b] = d + av[256];
}

extern "C" void kernel_launch(void* const* d_in, const int* in_sizes, int n_in,
                              void* d_out, int out_size, void* d_ws, size_t ws_size,
                              hipStream_t stream) {
  (void)in_sizes; (void)n_in; (void)out_size; (void)ws_size;
  const float* X     = (const float*)d_in[0];
  const float* Xmean = (const float*)d_in[1];
  const float* Wz    = (const float*)d_in[2];
  const float* bz    = (const float*)d_in[3];
  const float* Wr    = (const float*)d_in[4];
  const float* br    = (const float*)d_in[5];
  const float* Wh    = (const float*)d_in[6];
  const float* bh    = (const float*)d_in[7];
  const float* Wgx   = (const float*)d_in[8];
  const float* bgx   = (const float*)d_in[9];
  const float* Wgh   = (const float*)d_in[10];
  const float* bgh   = (const float*)d_in[11];
  const float* gamma = (const float*)d_in[12];
  const float* beta  = (const float*)d_in[13];
  const float* Wfc   = (const float*)d_in[14];
  const float* bfc   = (const float*)d_in[15];
  float* out = (float*)d_out;
  char* ws = (char*)d_ws;

  // workspace layout (bytes), total ~186.3 MB
  unsigned short* Upre = (unsigned short*)(ws + 0ull);           // 128*32*1024*16*2 = 134217728
  unsigned short* Cin  = (unsigned short*)(ws + 134217728ull);   // 128*512*384*2   = 50331648
  unsigned short* Wpre = (unsigned short*)(ws + 184549376ull);   // 1024*384*2      = 786432
  unsigned short* Wzrh = (unsigned short*)(ws + 185335808ull);   // 512*256*2       = 262144
  unsigned short* WhhP = (unsigned short*)(ws + 185597952ull);   // 256*256*2       = 131072
  float*          Bpre = (float*)(ws + 185729024ull);            // 1024*4
  float*          hT   = (float*)(ws + 185733120ull);            // 512*256*4
  float*          av   = (float*)(ws + 186257408ull);            // 257*4 (+pad)
  float*          XmT  = (float*)(ws + 186259456ull);            // 128*128*4

  pack_w<<<2372, 256, 0, stream>>>(Wz, Wr, Wh, Wgh, bz, br, bh, bgh, Xmean,
                                   Wpre, Wzrh, WhhP, Bpre, XmT);
  prep<<<1024, 128, 0, stream>>>(X, XmT, Wgx, bgx, Cin);
  u_gemm<<<1024, 256, 0, stream>>>(Cin, Wpre, Bpre, Upre);
  recur<<<32, 512, 0, stream>>>(Upre, Wzrh, WhhP, hT);
  bn_stats<<<1, 256, 0, stream>>>(hT, gamma, beta, Wfc, bfc, av);
  fin<<<512, 64, 0, stream>>>(hT, av, out);
}

// Round 3
// 567.513 us; speedup vs baseline: 1.7334x; 1.7334x over previous
//
#include <hip/hip_runtime.h>
#include <stdint.h>

// GRU-D forward, MI355X. B=512, steps S=128, T=128, H=256.
// R3: fix WhL staging row decomposition (R2's NaN: f>>4 should be f>>5 —
// OOB LDS writes). Added XOR swizzle to hb/qb (write+read sides).

#define NSTEP 128
#define NBAT  512

typedef __attribute__((ext_vector_type(8))) short bf16x8;
typedef __attribute__((ext_vector_type(4))) float f32x4;

__device__ __forceinline__ float bf2f(unsigned short u) {
  union { unsigned int i; float f; } v; v.i = ((unsigned int)u) << 16; return v.f;
}
__device__ __forceinline__ unsigned short f2bf(float f) {
  union { float f; unsigned int i; } v; v.f = f;
  unsigned int x = v.i;
  return (unsigned short)((x + 0x7fffu + ((x >> 16) & 1u)) >> 16);  // RNE
}
__device__ __forceinline__ float sigm(float x) { return 1.f / (1.f + __expf(-x)); }
__device__ __forceinline__ unsigned short us4_get(ushort4 v, int r) {
  return r == 0 ? v.x : r == 1 ? v.y : r == 2 ? v.z : v.w;
}
__device__ __forceinline__ void us4_set(ushort4& v, int r, unsigned short x) {
  if (r == 0) v.x = x; else if (r == 1) v.y = x; else if (r == 2) v.z = x; else v.w = x;
}

// ---------------------------------------------------------------------------
// pack_w: bf16 weight layouts + bias vector + transposed X_mean.
// ---------------------------------------------------------------------------
__global__ void pack_w(const float* __restrict__ Wz, const float* __restrict__ Wr,
                       const float* __restrict__ Wh, const float* __restrict__ Wgh,
                       const float* __restrict__ bz, const float* __restrict__ br,
                       const float* __restrict__ bh, const float* __restrict__ bgh,
                       const float* __restrict__ Xmean,
                       unsigned short* __restrict__ Wpre, unsigned short* __restrict__ Wzrh,
                       unsigned short* __restrict__ WhhP, float* __restrict__ Bpre,
                       float* __restrict__ XmT) {
  int id = blockIdx.x * 256 + threadIdx.x;
  if (id < 1024 * 384) {
    int j = id / 384, k = id % 384;
    float v = 0.f;
    if (j < 768) {
      const float* W = (j < 256) ? Wz : (j < 512) ? Wr : Wh;
      int jj = j & 255;
      if (k < 128)      v = W[jj * 512 + k];
      else if (k < 256) v = W[jj * 512 + 384 + (k - 128)];
    } else {
      int jj = j - 768;
      if (k >= 256) v = Wgh[jj * 128 + (k - 256)];
    }
    Wpre[id] = f2bf(v);
    return;
  }
  int id2 = id - 1024 * 384;
  if (id2 < 512 * 256) {
    int j = id2 >> 8, i = id2 & 255;
    float v = (j < 256) ? Wz[j * 512 + 128 + i] : Wr[(j - 256) * 512 + 128 + i];
    Wzrh[id2] = f2bf(v);
    return;
  }
  int id3 = id2 - 512 * 256;
  if (id3 < 256 * 256) {
    int j = id3 >> 8, i = id3 & 255;
    WhhP[id3] = f2bf(Wh[j * 512 + 128 + i]);
    return;
  }
  int id4 = id3 - 256 * 256;
  if (id4 < 1024) {
    float v = (id4 < 256) ? bz[id4] : (id4 < 512) ? br[id4 - 256]
            : (id4 < 768) ? bh[id4 - 512] : bgh[id4 - 768];
    Bpre[id4] = v;
    return;
  }
  int id5 = id4 - 1024;
  if (id5 < 128 * 128) {
    int t = id5 >> 7, s = id5 & 127;
    XmT[t * 128 + s] = Xmean[s * 128 + t];
  }
}

// ---------------------------------------------------------------------------
// prep: imputation + build Cin[s][b][k] bf16 (k: 0:128 x~, 128:256 m, 256:384 d).
// ---------------------------------------------------------------------------
__global__ __launch_bounds__(128) void prep(const float* __restrict__ X,
                                            const float* __restrict__ XmT,
                                            const float* __restrict__ Wgx,
                                            const float* __restrict__ bgx,
                                            unsigned short* __restrict__ Cin) {
  __shared__ unsigned short lx[64][132], lm[64][132], ldl[64][132];
  int b = blockIdx.x >> 1, tc = blockIdx.x & 1;
  int s = threadIdx.x;
  const float* Xb = X + (size_t)b * 384 * 128;
  for (int tt = 0; tt < 64; ++tt) {
    int t = tc * 64 + tt;
    float m = Xb[(3 * t + 0) * 128 + s];
    float x = Xb[(3 * t + 1) * 128 + s];
    float d = Xb[(3 * t + 2) * 128 + s];
    float wg = Wgx[t * 128 + t];
    float bg = bgx[t];
    float dx = __expf(-fmaxf(d * wg + bg, 0.f));
    float xm = XmT[t * 128 + s];
    float xt = m * x + (1.f - m) * (dx * x + (1.f - dx) * xm);
    lx[tt][s]  = f2bf(xt);
    lm[tt][s]  = f2bf(m);
    ldl[tt][s] = f2bf(d);
  }
  __syncthreads();
  for (int s0 = 0; s0 < 128; s0 += 2) {
    int ss = s0 + (threadIdx.x >> 6);
    int t  = threadIdx.x & 63;
    size_t base = ((size_t)ss * NBAT + b) * 384;
    Cin[base +       tc * 64 + t] = lx[t][ss];
    Cin[base + 128 + tc * 64 + t] = lm[t][ss];
    Cin[base + 256 + tc * 64 + t] = ldl[t][ss];
  }
}

// ---------------------------------------------------------------------------
// u_gemm: Upre[s][bt][b16][1024 j] bf16 = Cin @ Wpre^T + Bpre (batch-major).
// mfma(Wfrag, Xfrag): D row = j-in-tile (kq*4+reg), col = batch-in-group.
// ---------------------------------------------------------------------------
__global__ __launch_bounds__(256) void u_gemm(const unsigned short* __restrict__ Cin,
                                              const unsigned short* __restrict__ Wpre,
                                              const float* __restrict__ Bpre,
                                              unsigned short* __restrict__ Upre) {
  __shared__ unsigned short Ash[64][392];
  int s  = blockIdx.x >> 3;
  int bc = blockIdx.x & 7;
  int b0 = bc * 64;
  {
    int r = threadIdx.x >> 2, part = threadIdx.x & 3;
    const uint4* src = (const uint4*)(Cin + ((size_t)s * NBAT + b0 + r) * 384);
    uint4* dst = (uint4*)&Ash[r][0];
#pragma unroll
    for (int q = 0; q < 12; ++q) dst[part + q * 4] = src[part + q * 4];
  }
  __syncthreads();
  int wid = threadIdx.x >> 6, lane = threadIdx.x & 63;
  int col = lane & 15, kq = lane >> 4;

  if (wid < 3) {  // gate rows (z,r,h), K = 0:256
    int jbase = wid * 256;
    bf16x8 af[4][8];
#pragma unroll
    for (int mt = 0; mt < 4; ++mt)
#pragma unroll
      for (int kt = 0; kt < 8; ++kt)
        af[mt][kt] = *(const bf16x8*)&Ash[mt * 16 + col][kt * 32 + kq * 8];
    for (int jt = 0; jt < 16; ++jt) {
      int j0 = jbase + jt * 16;
      const unsigned short* wrow = Wpre + (size_t)(j0 + col) * 384 + kq * 8;
      f32x4 C[4] = {{0,0,0,0},{0,0,0,0},{0,0,0,0},{0,0,0,0}};
#pragma unroll
      for (int kt = 0; kt < 8; ++kt) {
        bf16x8 bw = *(const bf16x8*)(wrow + kt * 32);
        C[0] = __builtin_amdgcn_mfma_f32_16x16x32_bf16(bw, af[0][kt], C[0], 0, 0, 0);
        C[1] = __builtin_amdgcn_mfma_f32_16x16x32_bf16(bw, af[1][kt], C[1], 0, 0, 0);
        C[2] = __builtin_amdgcn_mfma_f32_16x16x32_bf16(bw, af[2][kt], C[2], 0, 0, 0);
        C[3] = __builtin_amdgcn_mfma_f32_16x16x32_bf16(bw, af[3][kt], C[3], 0, 0, 0);
      }
      int jv = j0 + kq * 4;
      float4 bias = *(const float4*)&Bpre[jv];
#pragma unroll
      for (int mt = 0; mt < 4; ++mt) {
        int bt = bc * 4 + mt;
        ushort4 o;
        o.x = f2bf(C[mt][0] + bias.x); o.y = f2bf(C[mt][1] + bias.y);
        o.z = f2bf(C[mt][2] + bias.z); o.w = f2bf(C[mt][3] + bias.w);
        *(ushort4*)(Upre + (((size_t)s * 32 + bt) * 16 + col) * 1024 + jv) = o;
      }
    }
  } else {  // g rows (dh preact), K = 256:384
    bf16x8 af[4][4];
#pragma unroll
    for (int mt = 0; mt < 4; ++mt)
#pragma unroll
      for (int kt = 0; kt < 4; ++kt)
        af[mt][kt] = *(const bf16x8*)&Ash[mt * 16 + col][256 + kt * 32 + kq * 8];
    for (int jt = 0; jt < 16; ++jt) {
      int j0 = 768 + jt * 16;
      const unsigned short* wrow = Wpre + (size_t)(j0 + col) * 384 + 256 + kq * 8;
      f32x4 C[4] = {{0,0,0,0},{0,0,0,0},{0,0,0,0},{0,0,0,0}};
#pragma unroll
      for (int kt = 0; kt < 4; ++kt) {
        bf16x8 bw = *(const bf16x8*)(wrow + kt * 32);
        C[0] = __builtin_amdgcn_mfma_f32_16x16x32_bf16(bw, af[0][kt], C[0], 0, 0, 0);
        C[1] = __builtin_amdgcn_mfma_f32_16x16x32_bf16(bw, af[1][kt], C[1], 0, 0, 0);
        C[2] = __builtin_amdgcn_mfma_f32_16x16x32_bf16(bw, af[2][kt], C[2], 0, 0, 0);
        C[3] = __builtin_amdgcn_mfma_f32_16x16x32_bf16(bw, af[3][kt], C[3], 0, 0, 0);
      }
      int jv = j0 + kq * 4;
      float4 bias = *(const float4*)&Bpre[jv];
#pragma unroll
      for (int mt = 0; mt < 4; ++mt) {
        int bt = bc * 4 + mt;
        ushort4 o;
        o.x = f2bf(C[mt][0] + bias.x); o.y = f2bf(C[mt][1] + bias.y);
        o.z = f2bf(C[mt][2] + bias.z); o.w = f2bf(C[mt][3] + bias.w);
        *(ushort4*)(Upre + (((size_t)s * 32 + bt) * 16 + col) * 1024 + jv) = o;
      }
    }
  }
}

// ---------------------------------------------------------------------------
// recur: 32 persistent blocks x 512 thr (8 waves), 16 batch rows/block.
// Wave w owns j-rows w*32..w*32+31 of every section; thread (col=batch,kq)
// owns (b=col, i=w*32+mt*16+kq*4+r). Wz/Wr frags in VGPRs, Whh in swizzled
// LDS, Ub prefetched to regs, h/z state in regs, decay fused into epilogue.
// ---------------------------------------------------------------------------
__global__ __launch_bounds__(512, 2) void recur(const unsigned short* __restrict__ Upre,
                                                const unsigned short* __restrict__ Wzrh,
                                                const unsigned short* __restrict__ WhhP,
                                                float* __restrict__ hT) {
  __shared__ unsigned short hb[16 * 256];   // decayed h bf16, 512B rows, swizzled
  __shared__ unsigned short qb[16 * 256];   // q = sig(r)*h bf16, swizzled
  __shared__ unsigned short WhL[65536];     // Whh, XOR-swizzled rows (131072 B)
  int bt = blockIdx.x, tid = threadIdx.x;
  int wid = tid >> 6, lane = tid & 63, col = lane & 15, kq = lane >> 4;
  const int hsw = (col & 7) << 4;

  // stage Whh -> LDS with swizzle: byte ^= (row&7)<<4. 8192 16B-chunks,
  // 32 chunks per 512B row (R2 bug: used 16/row -> OOB writes -> NaN).
#pragma unroll
  for (int i = 0; i < 16; ++i) {
    int f = tid + i * 512;
    int row = f >> 5, c = f & 31;
    bf16x8 v = *(const bf16x8*)(WhhP + (size_t)f * 8);
    *(bf16x8*)((char*)WhL + row * 512 + ((c * 16) ^ ((row & 7) << 4))) = v;
  }
  for (int i = tid; i < 16 * 256; i += 512) hb[i] = 0;

  // persistent z/r weight fragments (A-operand layout)
  bf16x8 wzf[2][8], wrf[2][8];
#pragma unroll
  for (int mt = 0; mt < 2; ++mt)
#pragma unroll
    for (int kt = 0; kt < 8; ++kt) {
      int j = wid * 32 + mt * 16 + col;
      wzf[mt][kt] = *(const bf16x8*)(Wzrh + (size_t)j * 256 + kt * 32 + kq * 8);
      wrf[mt][kt] = *(const bf16x8*)(Wzrh + (size_t)(256 + j) * 256 + kt * 32 + kq * 8);
    }

  const int joff0 = wid * 32 + kq * 4;
  const unsigned short* Ub0 = Upre + ((size_t)bt * 16 + col) * 1024;
  const size_t SS = 32 * 16 * 1024;  // per-step stride

  ushort4 uz[2], ur[2], uh[2], ug[2];
#pragma unroll
  for (int mt = 0; mt < 2; ++mt) {
    uz[mt] = *(const ushort4*)(Ub0 + 0   + joff0 + mt * 16);
    ur[mt] = *(const ushort4*)(Ub0 + 256 + joff0 + mt * 16);
    uh[mt] = *(const ushort4*)(Ub0 + 512 + joff0 + mt * 16);
    ug[mt] = *(const ushort4*)(Ub0 + SS + 768 + joff0 + mt * 16);  // step 1
  }
  f32x4 Hst[2] = {{0,0,0,0},{0,0,0,0}};
  float zk[2][4];
  __syncthreads();

  const char* hrow = (const char*)hb + col * 512;
  const char* qrow = (const char*)qb + col * 512;

  for (int s = 0; s < NSTEP; ++s) {
    // ---- GEMM1: z and r (interleaved independent chains) ----
    bf16x8 bop[8];
#pragma unroll
    for (int kt = 0; kt < 8; ++kt)
      bop[kt] = *(const bf16x8*)(hrow + ((kt * 64 + kq * 16) ^ hsw));
    f32x4 Cz[2], Cr[2];
#pragma unroll
    for (int mt = 0; mt < 2; ++mt) {
      f32x4 cz = {0,0,0,0}, cr = {0,0,0,0};
#pragma unroll
      for (int kt = 0; kt < 8; ++kt) {
        cz = __builtin_amdgcn_mfma_f32_16x16x32_bf16(wzf[mt][kt], bop[kt], cz, 0, 0, 0);
        cr = __builtin_amdgcn_mfma_f32_16x16x32_bf16(wrf[mt][kt], bop[kt], cr, 0, 0, 0);
      }
      Cz[mt] = cz; Cr[mt] = cr;
    }
    // epilogue: z kept in regs, q -> LDS (swizzled)
#pragma unroll
    for (int mt = 0; mt < 2; ++mt) {
      ushort4 q;
#pragma unroll
      for (int r = 0; r < 4; ++r) {
        float zv = sigm(Cz[mt][r] + bf2f(us4_get(uz[mt], r)));
        float rv = sigm(Cr[mt][r] + bf2f(us4_get(ur[mt], r)));
        zk[mt][r] = zv;
        us4_set(q, r, f2bf(rv * Hst[mt][r]));
      }
      *(ushort4*)((char*)qb + col * 512 + (((joff0 + mt * 16) * 2) ^ hsw)) = q;
    }
    // prefetch uz/ur for s+1
    {
      int sn = (s + 1 < NSTEP) ? s + 1 : NSTEP - 1;
      const unsigned short* ubn = Ub0 + (size_t)sn * SS;
#pragma unroll
      for (int mt = 0; mt < 2; ++mt) {
        uz[mt] = *(const ushort4*)(ubn + 0   + joff0 + mt * 16);
        ur[mt] = *(const ushort4*)(ubn + 256 + joff0 + mt * 16);
      }
    }
    __syncthreads();
    // ---- GEMM2: ht (Whh from swizzled LDS) ----
#pragma unroll
    for (int kt = 0; kt < 8; ++kt)
      bop[kt] = *(const bf16x8*)(qrow + ((kt * 64 + kq * 16) ^ hsw));
    f32x4 Ch[2];
    {
      int row0 = wid * 32 + col;
      const char* wb0 = (const char*)WhL + row0 * 512;
      const char* wb1 = wb0 + 16 * 512;
      int sw = (row0 & 7) << 4;
      f32x4 c0 = {0,0,0,0}, c1 = {0,0,0,0};
#pragma unroll
      for (int kt = 0; kt < 8; ++kt) {
        int ko = (kq * 16 + kt * 64) ^ sw;
        bf16x8 w0 = *(const bf16x8*)(wb0 + ko);
        bf16x8 w1 = *(const bf16x8*)(wb1 + ko);
        c0 = __builtin_amdgcn_mfma_f32_16x16x32_bf16(w0, bop[kt], c0, 0, 0, 0);
        c1 = __builtin_amdgcn_mfma_f32_16x16x32_bf16(w1, bop[kt], c1, 0, 0, 0);
      }
      Ch[0] = c0; Ch[1] = c1;
    }
    // epilogue: ht, state update, fused NEXT-step decay
#pragma unroll
    for (int mt = 0; mt < 2; ++mt) {
      float hn[4];
#pragma unroll
      for (int r = 0; r < 4; ++r) {
        float p = Ch[mt][r] + bf2f(us4_get(uh[mt], r));
        float e = __expf(2.f * p);
        float th = 1.f - 2.f / (e + 1.f);
        hn[r] = (1.f - zk[mt][r]) * Hst[mt][r] + zk[mt][r] * th;
      }
      if (s < NSTEP - 1) {
        ushort4 ho;
#pragma unroll
        for (int r = 0; r < 4; ++r) {
          float dh = __expf(-fmaxf(bf2f(us4_get(ug[mt], r)), 0.f));
          float Hn = hn[r] * dh;
          Hst[mt][r] = Hn;
          us4_set(ho, r, f2bf(Hn));
        }
        *(ushort4*)((char*)hb + col * 512 + (((joff0 + mt * 16) * 2) ^ hsw)) = ho;
      } else {
        float4 o4; o4.x = hn[0]; o4.y = hn[1]; o4.z = hn[2]; o4.w = hn[3];
        *(float4*)&hT[((size_t)bt * 16 + col) * 256 + joff0 + mt * 16] = o4;
      }
    }
    // prefetch uh for s+1, ug for s+2
    {
      int sn = (s + 1 < NSTEP) ? s + 1 : NSTEP - 1;
      int sg = (s + 2 < NSTEP) ? s + 2 : NSTEP - 1;
#pragma unroll
      for (int mt = 0; mt < 2; ++mt) {
        uh[mt] = *(const ushort4*)(Ub0 + (size_t)sn * SS + 512 + joff0 + mt * 16);
        ug[mt] = *(const ushort4*)(Ub0 + (size_t)sg * SS + 768 + joff0 + mt * 16);
      }
    }
    __syncthreads();
  }
}

// ---------------------------------------------------------------------------
// bn_stats + fin
// ---------------------------------------------------------------------------
__global__ __launch_bounds__(256) void bn_stats(const float* __restrict__ hT,
                                                const float* __restrict__ gamma,
                                                const float* __restrict__ beta,
                                                const float* __restrict__ Wfc,
                                                const float* __restrict__ bfc,
                                                float* __restrict__ av) {
  int j = threadIdx.x;
  float sum = 0.f, sum2 = 0.f;
#pragma unroll 8
  for (int b = 0; b < NBAT; ++b) {
    float v = hT[(size_t)b * 256 + j];
    sum += v; sum2 += v * v;
  }
  float mu = sum * (1.f / NBAT);
  float var = sum2 * (1.f / NBAT) - mu * mu;
  float a = gamma[j] * Wfc[j] * rsqrtf(var + 1e-5f);
  av[j] = a;
  __shared__ float red[256];
  red[j] = beta[j] * Wfc[j] - a * mu;
  __syncthreads();
  for (int o = 128; o; o >>= 1) {
    if (j < o) red[j] += red[j + o];
    __syncthreads();
  }
  if (j == 0) av[256] = red[0] + bfc[0];
}

__global__ __launch_bounds__(64) void fin(const float* __restrict__ hT,
                                          const float* __restrict__ av,
                                          float* __restrict__ out) {
  int b = blockIdx.x, lane = threadIdx.x;
  float4 hv = *(const float4*)&hT[(size_t)b * 256 + lane * 4];
  float4 a  = *(const float4*)&av[lane * 4];
  float d = hv.x * a.x + hv.y * a.y + hv.z * a.z + hv.w * a.w;
  for (int o = 32; o; o >>= 1) d += __shfl_down(d, o);
  if (lane == 0) out[b] = d + av[256];
}

extern "C" void kernel_launch(void* const* d_in, const int* in_sizes, int n_in,
                              void* d_out, int out_size, void* d_ws, size_t ws_size,
                              hipStream_t stream) {
  (void)in_sizes; (void)n_in; (void)out_size; (void)ws_size;
  const float* X     = (const float*)d_in[0];
  const float* Xmean = (const float*)d_in[1];
  const float* Wz    = (const float*)d_in[2];
  const float* bz    = (const float*)d_in[3];
  const float* Wr    = (const float*)d_in[4];
  const float* br    = (const float*)d_in[5];
  const float* Wh    = (const float*)d_in[6];
  const float* bh    = (const float*)d_in[7];
  const float* Wgx   = (const float*)d_in[8];
  const float* bgx   = (const float*)d_in[9];
  const float* Wgh   = (const float*)d_in[10];
  const float* bgh   = (const float*)d_in[11];
  const float* gamma = (const float*)d_in[12];
  const float* beta  = (const float*)d_in[13];
  const float* Wfc   = (const float*)d_in[14];
  const float* bfc   = (const float*)d_in[15];
  float* out = (float*)d_out;
  char* ws = (char*)d_ws;

  unsigned short* Upre = (unsigned short*)(ws + 0ull);           // 134217728 B
  unsigned short* Cin  = (unsigned short*)(ws + 134217728ull);   // 50331648 B
  unsigned short* Wpre = (unsigned short*)(ws + 184549376ull);   // 786432 B
  unsigned short* Wzrh = (unsigned short*)(ws + 185335808ull);   // 262144 B
  unsigned short* WhhP = (unsigned short*)(ws + 185597952ull);   // 131072 B
  float*          Bpre = (float*)(ws + 185729024ull);            // 4096 B
  float*          hT   = (float*)(ws + 185733120ull);            // 524288 B
  float*          av   = (float*)(ws + 186257408ull);            // 2048 B
  float*          XmT  = (float*)(ws + 186259456ull);            // 65536 B

  pack_w<<<2372, 256, 0, stream>>>(Wz, Wr, Wh, Wgh, bz, br, bh, bgh, Xmean,
                                   Wpre, Wzrh, WhhP, Bpre, XmT);
  prep<<<1024, 128, 0, stream>>>(X, XmT, Wgx, bgx, Cin);
  u_gemm<<<1024, 256, 0, stream>>>(Cin, Wpre, Bpre, Upre);
  recur<<<32, 512, 0, stream>>>(Upre, Wzrh, WhhP, hT);
  bn_stats<<<1, 256, 0, stream>>>(hT, gamma, beta, Wfc, bfc, av);
  fin<<<512, 64, 0, stream>>>(hT, av, out);
}

// Round 4
// 551.216 us; speedup vs baseline: 1.7847x; 1.0296x over previous
//
#include <hip/hip_runtime.h>
#include <stdint.h>

// GRU-D forward, MI355X. B=512, steps S=128, T=128, H=256.
// R4: recur — raw s_barrier (lgkmcnt-only drain; Upre prefetches stay in
// flight across barriers, consumed a full phase later) + v_cvt_pk_bf16_f32
// packing. Structure otherwise identical to R3 (passed, absmax 0.0078).

#define NSTEP 128
#define NBAT  512

typedef __attribute__((ext_vector_type(8))) short bf16x8;
typedef __attribute__((ext_vector_type(4))) float f32x4;

__device__ __forceinline__ float bf2f(unsigned short u) {
  union { unsigned int i; float f; } v; v.i = ((unsigned int)u) << 16; return v.f;
}
__device__ __forceinline__ unsigned short f2bf(float f) {
  union { float f; unsigned int i; } v; v.f = f;
  unsigned int x = v.i;
  return (unsigned short)((x + 0x7fffu + ((x >> 16) & 1u)) >> 16);  // RNE
}
__device__ __forceinline__ unsigned int cvt_pk_bf16(float lo, float hi) {
  unsigned int r;
  asm("v_cvt_pk_bf16_f32 %0, %1, %2" : "=v"(r) : "v"(lo), "v"(hi));
  return r;
}
__device__ __forceinline__ float sigm(float x) { return 1.f / (1.f + __expf(-x)); }
__device__ __forceinline__ unsigned short us4_get(ushort4 v, int r) {
  return r == 0 ? v.x : r == 1 ? v.y : r == 2 ? v.z : v.w;
}
// block-wide barrier WITHOUT vmcnt drain: LDS writes visible, global loads
// stay outstanding (m201 8-phase template pattern).
#define BSYNC() do { asm volatile("s_waitcnt lgkmcnt(0)" ::: "memory"); \
                     __builtin_amdgcn_s_barrier(); } while (0)

// ---------------------------------------------------------------------------
// pack_w: bf16 weight layouts + bias vector + transposed X_mean.
// ---------------------------------------------------------------------------
__global__ void pack_w(const float* __restrict__ Wz, const float* __restrict__ Wr,
                       const float* __restrict__ Wh, const float* __restrict__ Wgh,
                       const float* __restrict__ bz, const float* __restrict__ br,
                       const float* __restrict__ bh, const float* __restrict__ bgh,
                       const float* __restrict__ Xmean,
                       unsigned short* __restrict__ Wpre, unsigned short* __restrict__ Wzrh,
                       unsigned short* __restrict__ WhhP, float* __restrict__ Bpre,
                       float* __restrict__ XmT) {
  int id = blockIdx.x * 256 + threadIdx.x;
  if (id < 1024 * 384) {
    int j = id / 384, k = id % 384;
    float v = 0.f;
    if (j < 768) {
      const float* W = (j < 256) ? Wz : (j < 512) ? Wr : Wh;
      int jj = j & 255;
      if (k < 128)      v = W[jj * 512 + k];
      else if (k < 256) v = W[jj * 512 + 384 + (k - 128)];
    } else {
      int jj = j - 768;
      if (k >= 256) v = Wgh[jj * 128 + (k - 256)];
    }
    Wpre[id] = f2bf(v);
    return;
  }
  int id2 = id - 1024 * 384;
  if (id2 < 512 * 256) {
    int j = id2 >> 8, i = id2 & 255;
    float v = (j < 256) ? Wz[j * 512 + 128 + i] : Wr[(j - 256) * 512 + 128 + i];
    Wzrh[id2] = f2bf(v);
    return;
  }
  int id3 = id2 - 512 * 256;
  if (id3 < 256 * 256) {
    int j = id3 >> 8, i = id3 & 255;
    WhhP[id3] = f2bf(Wh[j * 512 + 128 + i]);
    return;
  }
  int id4 = id3 - 256 * 256;
  if (id4 < 1024) {
    float v = (id4 < 256) ? bz[id4] : (id4 < 512) ? br[id4 - 256]
            : (id4 < 768) ? bh[id4 - 512] : bgh[id4 - 768];
    Bpre[id4] = v;
    return;
  }
  int id5 = id4 - 1024;
  if (id5 < 128 * 128) {
    int t = id5 >> 7, s = id5 & 127;
    XmT[t * 128 + s] = Xmean[s * 128 + t];
  }
}

// ---------------------------------------------------------------------------
// prep: imputation + build Cin[s][b][k] bf16 (k: 0:128 x~, 128:256 m, 256:384 d).
// ---------------------------------------------------------------------------
__global__ __launch_bounds__(128) void prep(const float* __restrict__ X,
                                            const float* __restrict__ XmT,
                                            const float* __restrict__ Wgx,
                                            const float* __restrict__ bgx,
                                            unsigned short* __restrict__ Cin) {
  __shared__ unsigned short lx[64][132], lm[64][132], ldl[64][132];
  int b = blockIdx.x >> 1, tc = blockIdx.x & 1;
  int s = threadIdx.x;
  const float* Xb = X + (size_t)b * 384 * 128;
  for (int tt = 0; tt < 64; ++tt) {
    int t = tc * 64 + tt;
    float m = Xb[(3 * t + 0) * 128 + s];
    float x = Xb[(3 * t + 1) * 128 + s];
    float d = Xb[(3 * t + 2) * 128 + s];
    float wg = Wgx[t * 128 + t];
    float bg = bgx[t];
    float dx = __expf(-fmaxf(d * wg + bg, 0.f));
    float xm = XmT[t * 128 + s];
    float xt = m * x + (1.f - m) * (dx * x + (1.f - dx) * xm);
    lx[tt][s]  = f2bf(xt);
    lm[tt][s]  = f2bf(m);
    ldl[tt][s] = f2bf(d);
  }
  __syncthreads();
  for (int s0 = 0; s0 < 128; s0 += 2) {
    int ss = s0 + (threadIdx.x >> 6);
    int t  = threadIdx.x & 63;
    size_t base = ((size_t)ss * NBAT + b) * 384;
    Cin[base +       tc * 64 + t] = lx[t][ss];
    Cin[base + 128 + tc * 64 + t] = lm[t][ss];
    Cin[base + 256 + tc * 64 + t] = ldl[t][ss];
  }
}

// ---------------------------------------------------------------------------
// u_gemm: Upre[s][bt][b16][1024 j] bf16 = Cin @ Wpre^T + Bpre (batch-major).
// mfma(Wfrag, Xfrag): D row = j-in-tile (kq*4+reg), col = batch-in-group.
// ---------------------------------------------------------------------------
__global__ __launch_bounds__(256) void u_gemm(const unsigned short* __restrict__ Cin,
                                              const unsigned short* __restrict__ Wpre,
                                              const float* __restrict__ Bpre,
                                              unsigned short* __restrict__ Upre) {
  __shared__ unsigned short Ash[64][392];
  int s  = blockIdx.x >> 3;
  int bc = blockIdx.x & 7;
  int b0 = bc * 64;
  {
    int r = threadIdx.x >> 2, part = threadIdx.x & 3;
    const uint4* src = (const uint4*)(Cin + ((size_t)s * NBAT + b0 + r) * 384);
    uint4* dst = (uint4*)&Ash[r][0];
#pragma unroll
    for (int q = 0; q < 12; ++q) dst[part + q * 4] = src[part + q * 4];
  }
  __syncthreads();
  int wid = threadIdx.x >> 6, lane = threadIdx.x & 63;
  int col = lane & 15, kq = lane >> 4;

  if (wid < 3) {  // gate rows (z,r,h), K = 0:256
    int jbase = wid * 256;
    bf16x8 af[4][8];
#pragma unroll
    for (int mt = 0; mt < 4; ++mt)
#pragma unroll
      for (int kt = 0; kt < 8; ++kt)
        af[mt][kt] = *(const bf16x8*)&Ash[mt * 16 + col][kt * 32 + kq * 8];
    for (int jt = 0; jt < 16; ++jt) {
      int j0 = jbase + jt * 16;
      const unsigned short* wrow = Wpre + (size_t)(j0 + col) * 384 + kq * 8;
      f32x4 C[4] = {{0,0,0,0},{0,0,0,0},{0,0,0,0},{0,0,0,0}};
#pragma unroll
      for (int kt = 0; kt < 8; ++kt) {
        bf16x8 bw = *(const bf16x8*)(wrow + kt * 32);
        C[0] = __builtin_amdgcn_mfma_f32_16x16x32_bf16(bw, af[0][kt], C[0], 0, 0, 0);
        C[1] = __builtin_amdgcn_mfma_f32_16x16x32_bf16(bw, af[1][kt], C[1], 0, 0, 0);
        C[2] = __builtin_amdgcn_mfma_f32_16x16x32_bf16(bw, af[2][kt], C[2], 0, 0, 0);
        C[3] = __builtin_amdgcn_mfma_f32_16x16x32_bf16(bw, af[3][kt], C[3], 0, 0, 0);
      }
      int jv = j0 + kq * 4;
      float4 bias = *(const float4*)&Bpre[jv];
#pragma unroll
      for (int mt = 0; mt < 4; ++mt) {
        int bt = bc * 4 + mt;
        ushort4 o;
        o.x = f2bf(C[mt][0] + bias.x); o.y = f2bf(C[mt][1] + bias.y);
        o.z = f2bf(C[mt][2] + bias.z); o.w = f2bf(C[mt][3] + bias.w);
        *(ushort4*)(Upre + (((size_t)s * 32 + bt) * 16 + col) * 1024 + jv) = o;
      }
    }
  } else {  // g rows (dh preact), K = 256:384
    bf16x8 af[4][4];
#pragma unroll
    for (int mt = 0; mt < 4; ++mt)
#pragma unroll
      for (int kt = 0; kt < 4; ++kt)
        af[mt][kt] = *(const bf16x8*)&Ash[mt * 16 + col][256 + kt * 32 + kq * 8];
    for (int jt = 0; jt < 16; ++jt) {
      int j0 = 768 + jt * 16;
      const unsigned short* wrow = Wpre + (size_t)(j0 + col) * 384 + 256 + kq * 8;
      f32x4 C[4] = {{0,0,0,0},{0,0,0,0},{0,0,0,0},{0,0,0,0}};
#pragma unroll
      for (int kt = 0; kt < 4; ++kt) {
        bf16x8 bw = *(const bf16x8*)(wrow + kt * 32);
        C[0] = __builtin_amdgcn_mfma_f32_16x16x32_bf16(bw, af[0][kt], C[0], 0, 0, 0);
        C[1] = __builtin_amdgcn_mfma_f32_16x16x32_bf16(bw, af[1][kt], C[1], 0, 0, 0);
        C[2] = __builtin_amdgcn_mfma_f32_16x16x32_bf16(bw, af[2][kt], C[2], 0, 0, 0);
        C[3] = __builtin_amdgcn_mfma_f32_16x16x32_bf16(bw, af[3][kt], C[3], 0, 0, 0);
      }
      int jv = j0 + kq * 4;
      float4 bias = *(const float4*)&Bpre[jv];
#pragma unroll
      for (int mt = 0; mt < 4; ++mt) {
        int bt = bc * 4 + mt;
        ushort4 o;
        o.x = f2bf(C[mt][0] + bias.x); o.y = f2bf(C[mt][1] + bias.y);
        o.z = f2bf(C[mt][2] + bias.z); o.w = f2bf(C[mt][3] + bias.w);
        *(ushort4*)(Upre + (((size_t)s * 32 + bt) * 16 + col) * 1024 + jv) = o;
      }
    }
  }
}

// ---------------------------------------------------------------------------
// recur: 32 persistent blocks x 512 thr (8 waves), 16 batch rows/block.
// Wave w owns j-rows w*32..w*32+31; thread (col=batch,kq) owns
// (b=col, i=w*32+mt*16+kq*4+r). Wz/Wr in VGPRs, Whh in swizzled LDS,
// Ub prefetched (in flight across raw barriers), h/z state in regs.
// ---------------------------------------------------------------------------
__global__ __launch_bounds__(512, 2) void recur(const unsigned short* __restrict__ Upre,
                                                const unsigned short* __restrict__ Wzrh,
                                                const unsigned short* __restrict__ WhhP,
                                                float* __restrict__ hT) {
  __shared__ unsigned short hb[16 * 256];   // decayed h bf16, 512B rows, swizzled
  __shared__ unsigned short qb[16 * 256];   // q = sig(r)*h bf16, swizzled
  __shared__ unsigned short WhL[65536];     // Whh, XOR-swizzled rows (131072 B)
  int bt = blockIdx.x, tid = threadIdx.x;
  int wid = tid >> 6, lane = tid & 63, col = lane & 15, kq = lane >> 4;
  const int hsw = (col & 7) << 4;

  // stage Whh -> LDS, swizzle byte ^= (row&7)<<4; 32 16B-chunks per 512B row.
#pragma unroll
  for (int i = 0; i < 16; ++i) {
    int f = tid + i * 512;
    int row = f >> 5, c = f & 31;
    bf16x8 v = *(const bf16x8*)(WhhP + (size_t)f * 8);
    *(bf16x8*)((char*)WhL + row * 512 + ((c * 16) ^ ((row & 7) << 4))) = v;
  }
  for (int i = tid; i < 16 * 256; i += 512) hb[i] = 0;

  // persistent z/r weight fragments (A-operand layout)
  bf16x8 wzf[2][8], wrf[2][8];
#pragma unroll
  for (int mt = 0; mt < 2; ++mt)
#pragma unroll
    for (int kt = 0; kt < 8; ++kt) {
      int j = wid * 32 + mt * 16 + col;
      wzf[mt][kt] = *(const bf16x8*)(Wzrh + (size_t)j * 256 + kt * 32 + kq * 8);
      wrf[mt][kt] = *(const bf16x8*)(Wzrh + (size_t)(256 + j) * 256 + kt * 32 + kq * 8);
    }

  const int joff0 = wid * 32 + kq * 4;
  const unsigned short* Ub0 = Upre + ((size_t)bt * 16 + col) * 1024;
  const size_t SS = 32 * 16 * 1024;  // per-step stride

  ushort4 uz[2], ur[2], uh[2], ug[2];
#pragma unroll
  for (int mt = 0; mt < 2; ++mt) {
    uz[mt] = *(const ushort4*)(Ub0 + 0   + joff0 + mt * 16);
    ur[mt] = *(const ushort4*)(Ub0 + 256 + joff0 + mt * 16);
    uh[mt] = *(const ushort4*)(Ub0 + 512 + joff0 + mt * 16);
    ug[mt] = *(const ushort4*)(Ub0 + SS + 768 + joff0 + mt * 16);  // step 1
  }
  f32x4 Hst[2] = {{0,0,0,0},{0,0,0,0}};
  float zk[2][4];
  BSYNC();

  const char* hrow = (const char*)hb + col * 512;
  const char* qrow = (const char*)qb + col * 512;

  for (int s = 0; s < NSTEP; ++s) {
    // ---- GEMM1: z and r (4 independent accumulation chains) ----
    bf16x8 bop[8];
#pragma unroll
    for (int kt = 0; kt < 8; ++kt)
      bop[kt] = *(const bf16x8*)(hrow + ((kt * 64 + kq * 16) ^ hsw));
    f32x4 Cz[2], Cr[2];
#pragma unroll
    for (int mt = 0; mt < 2; ++mt) {
      f32x4 cz = {0,0,0,0}, cr = {0,0,0,0};
#pragma unroll
      for (int kt = 0; kt < 8; ++kt) {
        cz = __builtin_amdgcn_mfma_f32_16x16x32_bf16(wzf[mt][kt], bop[kt], cz, 0, 0, 0);
        cr = __builtin_amdgcn_mfma_f32_16x16x32_bf16(wrf[mt][kt], bop[kt], cr, 0, 0, 0);
      }
      Cz[mt] = cz; Cr[mt] = cr;
    }
    // epilogue: z kept in regs, q -> LDS (swizzled) via cvt_pk
#pragma unroll
    for (int mt = 0; mt < 2; ++mt) {
      float qv[4];
#pragma unroll
      for (int r = 0; r < 4; ++r) {
        float zv = sigm(Cz[mt][r] + bf2f(us4_get(uz[mt], r)));
        float rv = sigm(Cr[mt][r] + bf2f(us4_get(ur[mt], r)));
        zk[mt][r] = zv;
        qv[r] = rv * Hst[mt][r];
      }
      uint2 qw;
      qw.x = cvt_pk_bf16(qv[0], qv[1]);
      qw.y = cvt_pk_bf16(qv[2], qv[3]);
      *(uint2*)((char*)qb + col * 512 + (((joff0 + mt * 16) * 2) ^ hsw)) = qw;
    }
    // prefetch uz/ur for s+1 (stays in flight across the raw barrier)
    {
      int sn = (s + 1 < NSTEP) ? s + 1 : NSTEP - 1;
      const unsigned short* ubn = Ub0 + (size_t)sn * SS;
#pragma unroll
      for (int mt = 0; mt < 2; ++mt) {
        uz[mt] = *(const ushort4*)(ubn + 0   + joff0 + mt * 16);
        ur[mt] = *(const ushort4*)(ubn + 256 + joff0 + mt * 16);
      }
    }
    BSYNC();
    // ---- GEMM2: ht (Whh from swizzled LDS) ----
#pragma unroll
    for (int kt = 0; kt < 8; ++kt)
      bop[kt] = *(const bf16x8*)(qrow + ((kt * 64 + kq * 16) ^ hsw));
    f32x4 Ch[2];
    {
      int row0 = wid * 32 + col;
      const char* wb0 = (const char*)WhL + row0 * 512;
      const char* wb1 = wb0 + 16 * 512;
      int sw = (row0 & 7) << 4;
      f32x4 c0 = {0,0,0,0}, c1 = {0,0,0,0};
#pragma unroll
      for (int kt = 0; kt < 8; ++kt) {
        int ko = (kq * 16 + kt * 64) ^ sw;
        bf16x8 w0 = *(const bf16x8*)(wb0 + ko);
        bf16x8 w1 = *(const bf16x8*)(wb1 + ko);
        c0 = __builtin_amdgcn_mfma_f32_16x16x32_bf16(w0, bop[kt], c0, 0, 0, 0);
        c1 = __builtin_amdgcn_mfma_f32_16x16x32_bf16(w1, bop[kt], c1, 0, 0, 0);
      }
      Ch[0] = c0; Ch[1] = c1;
    }
    // epilogue: ht, state update, fused NEXT-step decay
#pragma unroll
    for (int mt = 0; mt < 2; ++mt) {
      float hn[4];
#pragma unroll
      for (int r = 0; r < 4; ++r) {
        float p = Ch[mt][r] + bf2f(us4_get(uh[mt], r));
        float e = __expf(2.f * p);
        float th = 1.f - 2.f / (e + 1.f);
        hn[r] = (1.f - zk[mt][r]) * Hst[mt][r] + zk[mt][r] * th;
      }
      if (s < NSTEP - 1) {
        float Hn[4];
#pragma unroll
        for (int r = 0; r < 4; ++r) {
          float dh = __expf(-fmaxf(bf2f(us4_get(ug[mt], r)), 0.f));
          Hn[r] = hn[r] * dh;
          Hst[mt][r] = Hn[r];
        }
        uint2 hw;
        hw.x = cvt_pk_bf16(Hn[0], Hn[1]);
        hw.y = cvt_pk_bf16(Hn[2], Hn[3]);
        *(uint2*)((char*)hb + col * 512 + (((joff0 + mt * 16) * 2) ^ hsw)) = hw;
      } else {
        float4 o4; o4.x = hn[0]; o4.y = hn[1]; o4.z = hn[2]; o4.w = hn[3];
        *(float4*)&hT[((size_t)bt * 16 + col) * 256 + joff0 + mt * 16] = o4;
      }
    }
    // prefetch uh for s+1, ug for s+2 (in flight across the raw barrier)
    {
      int sn = (s + 1 < NSTEP) ? s + 1 : NSTEP - 1;
      int sg = (s + 2 < NSTEP) ? s + 2 : NSTEP - 1;
#pragma unroll
      for (int mt = 0; mt < 2; ++mt) {
        uh[mt] = *(const ushort4*)(Ub0 + (size_t)sn * SS + 512 + joff0 + mt * 16);
        ug[mt] = *(const ushort4*)(Ub0 + (size_t)sg * SS + 768 + joff0 + mt * 16);
      }
    }
    BSYNC();
  }
}

// ---------------------------------------------------------------------------
// bn_stats + fin
// ---------------------------------------------------------------------------
__global__ __launch_bounds__(256) void bn_stats(const float* __restrict__ hT,
                                                const float* __restrict__ gamma,
                                                const float* __restrict__ beta,
                                                const float* __restrict__ Wfc,
                                                const float* __restrict__ bfc,
                                                float* __restrict__ av) {
  int j = threadIdx.x;
  float sum = 0.f, sum2 = 0.f;
#pragma unroll 8
  for (int b = 0; b < NBAT; ++b) {
    float v = hT[(size_t)b * 256 + j];
    sum += v; sum2 += v * v;
  }
  float mu = sum * (1.f / NBAT);
  float var = sum2 * (1.f / NBAT) - mu * mu;
  float a = gamma[j] * Wfc[j] * rsqrtf(var + 1e-5f);
  av[j] = a;
  __shared__ float red[256];
  red[j] = beta[j] * Wfc[j] - a * mu;
  __syncthreads();
  for (int o = 128; o; o >>= 1) {
    if (j < o) red[j] += red[j + o];
    __syncthreads();
  }
  if (j == 0) av[256] = red[0] + bfc[0];
}

__global__ __launch_bounds__(64) void fin(const float* __restrict__ hT,
                                          const float* __restrict__ av,
                                          float* __restrict__ out) {
  int b = blockIdx.x, lane = threadIdx.x;
  float4 hv = *(const float4*)&hT[(size_t)b * 256 + lane * 4];
  float4 a  = *(const float4*)&av[lane * 4];
  float d = hv.x * a.x + hv.y * a.y + hv.z * a.z + hv.w * a.w;
  for (int o = 32; o; o >>= 1) d += __shfl_down(d, o);
  if (lane == 0) out[b] = d + av[256];
}

extern "C" void kernel_launch(void* const* d_in, const int* in_sizes, int n_in,
                              void* d_out, int out_size, void* d_ws, size_t ws_size,
                              hipStream_t stream) {
  (void)in_sizes; (void)n_in; (void)out_size; (void)ws_size;
  const float* X     = (const float*)d_in[0];
  const float* Xmean = (const float*)d_in[1];
  const float* Wz    = (const float*)d_in[2];
  const float* bz    = (const float*)d_in[3];
  const float* Wr    = (const float*)d_in[4];
  const float* br    = (const float*)d_in[5];
  const float* Wh    = (const float*)d_in[6];
  const float* bh    = (const float*)d_in[7];
  const float* Wgx   = (const float*)d_in[8];
  const float* bgx   = (const float*)d_in[9];
  const float* Wgh   = (const float*)d_in[10];
  const float* bgh   = (const float*)d_in[11];
  const float* gamma = (const float*)d_in[12];
  const float* beta  = (const float*)d_in[13];
  const float* Wfc   = (const float*)d_in[14];
  const float* bfc   = (const float*)d_in[15];
  float* out = (float*)d_out;
  char* ws = (char*)d_ws;

  unsigned short* Upre = (unsigned short*)(ws + 0ull);           // 134217728 B
  unsigned short* Cin  = (unsigned short*)(ws + 134217728ull);   // 50331648 B
  unsigned short* Wpre = (unsigned short*)(ws + 184549376ull);   // 786432 B
  unsigned short* Wzrh = (unsigned short*)(ws + 185335808ull);   // 262144 B
  unsigned short* WhhP = (unsigned short*)(ws + 185597952ull);   // 131072 B
  float*          Bpre = (float*)(ws + 185729024ull);            // 4096 B
  float*          hT   = (float*)(ws + 185733120ull);            // 524288 B
  float*          av   = (float*)(ws + 186257408ull);            // 2048 B
  float*          XmT  = (float*)(ws + 186259456ull);            // 65536 B

  pack_w<<<2372, 256, 0, stream>>>(Wz, Wr, Wh, Wgh, bz, br, bh, bgh, Xmean,
                                   Wpre, Wzrh, WhhP, Bpre, XmT);
  prep<<<1024, 128, 0, stream>>>(X, XmT, Wgx, bgx, Cin);
  u_gemm<<<1024, 256, 0, stream>>>(Cin, Wpre, Bpre, Upre);
  recur<<<32, 512, 0, stream>>>(Upre, Wzrh, WhhP, hT);
  bn_stats<<<1, 256, 0, stream>>>(hT, gamma, beta, Wfc, bfc, av);
  fin<<<512, 64, 0, stream>>>(hT, av, out);
}

// Round 5
// 550.270 us; speedup vs baseline: 1.7877x; 1.0017x over previous
//
#include <hip/hip_runtime.h>
#include <stdint.h>

// GRU-D forward, MI355X. B=512, steps S=128, T=128, H=256.
// R5: recur — PIN wz/wr weight fragments in VGPRs (R4 evidence: VGPR_Count=120
// < 128 needed for weights alone => compiler rematerialized the global loads
// inside the step loop). Stream bop reads; pointer-bump Upre prefetch
// (overshoot lands in Cin region, unused). Rest identical to R4 (passed).

#define NSTEP 128
#define NBAT  512

typedef __attribute__((ext_vector_type(8))) short bf16x8;
typedef __attribute__((ext_vector_type(4))) float f32x4;

__device__ __forceinline__ float bf2f(unsigned short u) {
  union { unsigned int i; float f; } v; v.i = ((unsigned int)u) << 16; return v.f;
}
__device__ __forceinline__ unsigned short f2bf(float f) {
  union { float f; unsigned int i; } v; v.f = f;
  unsigned int x = v.i;
  return (unsigned short)((x + 0x7fffu + ((x >> 16) & 1u)) >> 16);  // RNE
}
__device__ __forceinline__ unsigned int cvt_pk_bf16(float lo, float hi) {
  unsigned int r;
  asm("v_cvt_pk_bf16_f32 %0, %1, %2" : "=v"(r) : "v"(lo), "v"(hi));
  return r;
}
__device__ __forceinline__ float sigm(float x) { return 1.f / (1.f + __expf(-x)); }
__device__ __forceinline__ unsigned short us4_get(ushort4 v, int r) {
  return r == 0 ? v.x : r == 1 ? v.y : r == 2 ? v.z : v.w;
}
// value-neutral pin: makes frag an asm output so its defining load can't be
// rematerialized inside the loop.
#define PINV(x) asm volatile("" : "+v"(x))
// block barrier WITHOUT vmcnt drain (global loads stay in flight).
#define BSYNC() do { asm volatile("s_waitcnt lgkmcnt(0)" ::: "memory"); \
                     __builtin_amdgcn_s_barrier(); } while (0)

// ---------------------------------------------------------------------------
// pack_w: bf16 weight layouts + bias vector + transposed X_mean.
// ---------------------------------------------------------------------------
__global__ void pack_w(const float* __restrict__ Wz, const float* __restrict__ Wr,
                       const float* __restrict__ Wh, const float* __restrict__ Wgh,
                       const float* __restrict__ bz, const float* __restrict__ br,
                       const float* __restrict__ bh, const float* __restrict__ bgh,
                       const float* __restrict__ Xmean,
                       unsigned short* __restrict__ Wpre, unsigned short* __restrict__ Wzrh,
                       unsigned short* __restrict__ WhhP, float* __restrict__ Bpre,
                       float* __restrict__ XmT) {
  int id = blockIdx.x * 256 + threadIdx.x;
  if (id < 1024 * 384) {
    int j = id / 384, k = id % 384;
    float v = 0.f;
    if (j < 768) {
      const float* W = (j < 256) ? Wz : (j < 512) ? Wr : Wh;
      int jj = j & 255;
      if (k < 128)      v = W[jj * 512 + k];
      else if (k < 256) v = W[jj * 512 + 384 + (k - 128)];
    } else {
      int jj = j - 768;
      if (k >= 256) v = Wgh[jj * 128 + (k - 256)];
    }
    Wpre[id] = f2bf(v);
    return;
  }
  int id2 = id - 1024 * 384;
  if (id2 < 512 * 256) {
    int j = id2 >> 8, i = id2 & 255;
    float v = (j < 256) ? Wz[j * 512 + 128 + i] : Wr[(j - 256) * 512 + 128 + i];
    Wzrh[id2] = f2bf(v);
    return;
  }
  int id3 = id2 - 512 * 256;
  if (id3 < 256 * 256) {
    int j = id3 >> 8, i = id3 & 255;
    WhhP[id3] = f2bf(Wh[j * 512 + 128 + i]);
    return;
  }
  int id4 = id3 - 256 * 256;
  if (id4 < 1024) {
    float v = (id4 < 256) ? bz[id4] : (id4 < 512) ? br[id4 - 256]
            : (id4 < 768) ? bh[id4 - 512] : bgh[id4 - 768];
    Bpre[id4] = v;
    return;
  }
  int id5 = id4 - 1024;
  if (id5 < 128 * 128) {
    int t = id5 >> 7, s = id5 & 127;
    XmT[t * 128 + s] = Xmean[s * 128 + t];
  }
}

// ---------------------------------------------------------------------------
// prep: imputation + build Cin[s][b][k] bf16 (k: 0:128 x~, 128:256 m, 256:384 d).
// ---------------------------------------------------------------------------
__global__ __launch_bounds__(128) void prep(const float* __restrict__ X,
                                            const float* __restrict__ XmT,
                                            const float* __restrict__ Wgx,
                                            const float* __restrict__ bgx,
                                            unsigned short* __restrict__ Cin) {
  __shared__ unsigned short lx[64][132], lm[64][132], ldl[64][132];
  int b = blockIdx.x >> 1, tc = blockIdx.x & 1;
  int s = threadIdx.x;
  const float* Xb = X + (size_t)b * 384 * 128;
  for (int tt = 0; tt < 64; ++tt) {
    int t = tc * 64 + tt;
    float m = Xb[(3 * t + 0) * 128 + s];
    float x = Xb[(3 * t + 1) * 128 + s];
    float d = Xb[(3 * t + 2) * 128 + s];
    float wg = Wgx[t * 128 + t];
    float bg = bgx[t];
    float dx = __expf(-fmaxf(d * wg + bg, 0.f));
    float xm = XmT[t * 128 + s];
    float xt = m * x + (1.f - m) * (dx * x + (1.f - dx) * xm);
    lx[tt][s]  = f2bf(xt);
    lm[tt][s]  = f2bf(m);
    ldl[tt][s] = f2bf(d);
  }
  __syncthreads();
  for (int s0 = 0; s0 < 128; s0 += 2) {
    int ss = s0 + (threadIdx.x >> 6);
    int t  = threadIdx.x & 63;
    size_t base = ((size_t)ss * NBAT + b) * 384;
    Cin[base +       tc * 64 + t] = lx[t][ss];
    Cin[base + 128 + tc * 64 + t] = lm[t][ss];
    Cin[base + 256 + tc * 64 + t] = ldl[t][ss];
  }
}

// ---------------------------------------------------------------------------
// u_gemm: Upre[s][bt][b16][1024 j] bf16 = Cin @ Wpre^T + Bpre (batch-major).
// ---------------------------------------------------------------------------
__global__ __launch_bounds__(256) void u_gemm(const unsigned short* __restrict__ Cin,
                                              const unsigned short* __restrict__ Wpre,
                                              const float* __restrict__ Bpre,
                                              unsigned short* __restrict__ Upre) {
  __shared__ unsigned short Ash[64][392];
  int s  = blockIdx.x >> 3;
  int bc = blockIdx.x & 7;
  int b0 = bc * 64;
  {
    int r = threadIdx.x >> 2, part = threadIdx.x & 3;
    const uint4* src = (const uint4*)(Cin + ((size_t)s * NBAT + b0 + r) * 384);
    uint4* dst = (uint4*)&Ash[r][0];
#pragma unroll
    for (int q = 0; q < 12; ++q) dst[part + q * 4] = src[part + q * 4];
  }
  __syncthreads();
  int wid = threadIdx.x >> 6, lane = threadIdx.x & 63;
  int col = lane & 15, kq = lane >> 4;

  if (wid < 3) {  // gate rows (z,r,h), K = 0:256
    int jbase = wid * 256;
    bf16x8 af[4][8];
#pragma unroll
    for (int mt = 0; mt < 4; ++mt)
#pragma unroll
      for (int kt = 0; kt < 8; ++kt)
        af[mt][kt] = *(const bf16x8*)&Ash[mt * 16 + col][kt * 32 + kq * 8];
    for (int jt = 0; jt < 16; ++jt) {
      int j0 = jbase + jt * 16;
      const unsigned short* wrow = Wpre + (size_t)(j0 + col) * 384 + kq * 8;
      f32x4 C[4] = {{0,0,0,0},{0,0,0,0},{0,0,0,0},{0,0,0,0}};
#pragma unroll
      for (int kt = 0; kt < 8; ++kt) {
        bf16x8 bw = *(const bf16x8*)(wrow + kt * 32);
        C[0] = __builtin_amdgcn_mfma_f32_16x16x32_bf16(bw, af[0][kt], C[0], 0, 0, 0);
        C[1] = __builtin_amdgcn_mfma_f32_16x16x32_bf16(bw, af[1][kt], C[1], 0, 0, 0);
        C[2] = __builtin_amdgcn_mfma_f32_16x16x32_bf16(bw, af[2][kt], C[2], 0, 0, 0);
        C[3] = __builtin_amdgcn_mfma_f32_16x16x32_bf16(bw, af[3][kt], C[3], 0, 0, 0);
      }
      int jv = j0 + kq * 4;
      float4 bias = *(const float4*)&Bpre[jv];
#pragma unroll
      for (int mt = 0; mt < 4; ++mt) {
        int bt = bc * 4 + mt;
        ushort4 o;
        o.x = f2bf(C[mt][0] + bias.x); o.y = f2bf(C[mt][1] + bias.y);
        o.z = f2bf(C[mt][2] + bias.z); o.w = f2bf(C[mt][3] + bias.w);
        *(ushort4*)(Upre + (((size_t)s * 32 + bt) * 16 + col) * 1024 + jv) = o;
      }
    }
  } else {  // g rows (dh preact), K = 256:384
    bf16x8 af[4][4];
#pragma unroll
    for (int mt = 0; mt < 4; ++mt)
#pragma unroll
      for (int kt = 0; kt < 4; ++kt)
        af[mt][kt] = *(const bf16x8*)&Ash[mt * 16 + col][256 + kt * 32 + kq * 8];
    for (int jt = 0; jt < 16; ++jt) {
      int j0 = 768 + jt * 16;
      const unsigned short* wrow = Wpre + (size_t)(j0 + col) * 384 + 256 + kq * 8;
      f32x4 C[4] = {{0,0,0,0},{0,0,0,0},{0,0,0,0},{0,0,0,0}};
#pragma unroll
      for (int kt = 0; kt < 4; ++kt) {
        bf16x8 bw = *(const bf16x8*)(wrow + kt * 32);
        C[0] = __builtin_amdgcn_mfma_f32_16x16x32_bf16(bw, af[0][kt], C[0], 0, 0, 0);
        C[1] = __builtin_amdgcn_mfma_f32_16x16x32_bf16(bw, af[1][kt], C[1], 0, 0, 0);
        C[2] = __builtin_amdgcn_mfma_f32_16x16x32_bf16(bw, af[2][kt], C[2], 0, 0, 0);
        C[3] = __builtin_amdgcn_mfma_f32_16x16x32_bf16(bw, af[3][kt], C[3], 0, 0, 0);
      }
      int jv = j0 + kq * 4;
      float4 bias = *(const float4*)&Bpre[jv];
#pragma unroll
      for (int mt = 0; mt < 4; ++mt) {
        int bt = bc * 4 + mt;
        ushort4 o;
        o.x = f2bf(C[mt][0] + bias.x); o.y = f2bf(C[mt][1] + bias.y);
        o.z = f2bf(C[mt][2] + bias.z); o.w = f2bf(C[mt][3] + bias.w);
        *(ushort4*)(Upre + (((size_t)s * 32 + bt) * 16 + col) * 1024 + jv) = o;
      }
    }
  }
}

// ---------------------------------------------------------------------------
// recur: 32 persistent blocks x 512 thr (8 waves), 16 batch rows/block.
// Wz/Wr fragments PINNED in VGPRs; Whh in swizzled LDS; Ub via bumped
// pointer prefetch (in flight across raw barriers); h/z state in regs.
// ---------------------------------------------------------------------------
__global__ __launch_bounds__(512, 2) void recur(const unsigned short* __restrict__ Upre,
                                                const unsigned short* __restrict__ Wzrh,
                                                const unsigned short* __restrict__ WhhP,
                                                float* __restrict__ hT) {
  __shared__ unsigned short hb[16 * 256];   // decayed h bf16, 512B rows, swizzled
  __shared__ unsigned short qb[16 * 256];   // q = sig(r)*h bf16, swizzled
  __shared__ unsigned short WhL[65536];     // Whh, XOR-swizzled rows (131072 B)
  int bt = blockIdx.x, tid = threadIdx.x;
  int wid = tid >> 6, lane = tid & 63, col = lane & 15, kq = lane >> 4;
  const int hsw = (col & 7) << 4;

  // stage Whh -> LDS, swizzle byte ^= (row&7)<<4; 32 16B-chunks per 512B row.
#pragma unroll
  for (int i = 0; i < 16; ++i) {
    int f = tid + i * 512;
    int row = f >> 5, c = f & 31;
    bf16x8 v = *(const bf16x8*)(WhhP + (size_t)f * 8);
    *(bf16x8*)((char*)WhL + row * 512 + ((c * 16) ^ ((row & 7) << 4))) = v;
  }
  for (int i = tid; i < 16 * 256; i += 512) hb[i] = 0;

  // persistent z/r weight fragments (A-operand layout), pinned resident.
  bf16x8 wzf[2][8], wrf[2][8];
#pragma unroll
  for (int mt = 0; mt < 2; ++mt)
#pragma unroll
    for (int kt = 0; kt < 8; ++kt) {
      int j = wid * 32 + mt * 16 + col;
      wzf[mt][kt] = *(const bf16x8*)(Wzrh + (size_t)j * 256 + kt * 32 + kq * 8);
      wrf[mt][kt] = *(const bf16x8*)(Wzrh + (size_t)(256 + j) * 256 + kt * 32 + kq * 8);
      PINV(wzf[mt][kt]);
      PINV(wrf[mt][kt]);
    }

  const int joff0 = wid * 32 + kq * 4;
  const unsigned short* Ub0 = Upre + ((size_t)bt * 16 + col) * 1024;
  const size_t SS = 32 * 16 * 1024;  // per-step stride (shorts)

  ushort4 uz[2], ur[2], uh[2], ug[2];
#pragma unroll
  for (int mt = 0; mt < 2; ++mt) {
    uz[mt] = *(const ushort4*)(Ub0 + 0   + joff0 + mt * 16);
    ur[mt] = *(const ushort4*)(Ub0 + 256 + joff0 + mt * 16);
    uh[mt] = *(const ushort4*)(Ub0 + 512 + joff0 + mt * 16);
    ug[mt] = *(const ushort4*)(Ub0 + SS + 768 + joff0 + mt * 16);  // step 1
  }
  const unsigned short* pnext = Ub0 + SS + joff0;  // step s+1 base (+joff0)
  f32x4 Hst[2] = {{0,0,0,0},{0,0,0,0}};
  float zk[2][4];
  BSYNC();

  const char* hrow = (const char*)hb + col * 512;
  const char* qrow = (const char*)qb + col * 512;

  for (int s = 0; s < NSTEP; ++s) {
    // ---- GEMM1: z and r (4 independent accumulation chains) ----
    f32x4 Cz[2] = {{0,0,0,0},{0,0,0,0}}, Cr[2] = {{0,0,0,0},{0,0,0,0}};
#pragma unroll
    for (int kt = 0; kt < 8; ++kt) {
      bf16x8 b = *(const bf16x8*)(hrow + ((kt * 64 + kq * 16) ^ hsw));
      Cz[0] = __builtin_amdgcn_mfma_f32_16x16x32_bf16(wzf[0][kt], b, Cz[0], 0, 0, 0);
      Cr[0] = __builtin_amdgcn_mfma_f32_16x16x32_bf16(wrf[0][kt], b, Cr[0], 0, 0, 0);
      Cz[1] = __builtin_amdgcn_mfma_f32_16x16x32_bf16(wzf[1][kt], b, Cz[1], 0, 0, 0);
      Cr[1] = __builtin_amdgcn_mfma_f32_16x16x32_bf16(wrf[1][kt], b, Cr[1], 0, 0, 0);
    }
    // epilogue: z kept in regs, q -> LDS (swizzled) via cvt_pk
#pragma unroll
    for (int mt = 0; mt < 2; ++mt) {
      float qv[4];
#pragma unroll
      for (int r = 0; r < 4; ++r) {
        float zv = sigm(Cz[mt][r] + bf2f(us4_get(uz[mt], r)));
        float rv = sigm(Cr[mt][r] + bf2f(us4_get(ur[mt], r)));
        zk[mt][r] = zv;
        qv[r] = rv * Hst[mt][r];
      }
      uint2 qw;
      qw.x = cvt_pk_bf16(qv[0], qv[1]);
      qw.y = cvt_pk_bf16(qv[2], qv[3]);
      *(uint2*)((char*)qb + col * 512 + (((joff0 + mt * 16) * 2) ^ hsw)) = qw;
    }
    // prefetch uz/ur for s+1 (stays in flight across the raw barrier).
    // At s=127 this reads step 128 (lands in Cin region, unused).
#pragma unroll
    for (int mt = 0; mt < 2; ++mt) {
      uz[mt] = *(const ushort4*)(pnext + 0   + mt * 16);
      ur[mt] = *(const ushort4*)(pnext + 256 + mt * 16);
    }
    BSYNC();
    // ---- GEMM2: ht (Whh from swizzled LDS) ----
    f32x4 Ch[2] = {{0,0,0,0},{0,0,0,0}};
    {
      int row0 = wid * 32 + col;
      const char* wb0 = (const char*)WhL + row0 * 512;
      const char* wb1 = wb0 + 16 * 512;
      int sw = (row0 & 7) << 4;
#pragma unroll
      for (int kt = 0; kt < 8; ++kt) {
        int ko = (kq * 16 + kt * 64) ^ sw;
        bf16x8 b = *(const bf16x8*)(qrow + ((kt * 64 + kq * 16) ^ hsw));
        bf16x8 w0 = *(const bf16x8*)(wb0 + ko);
        bf16x8 w1 = *(const bf16x8*)(wb1 + ko);
        Ch[0] = __builtin_amdgcn_mfma_f32_16x16x32_bf16(w0, b, Ch[0], 0, 0, 0);
        Ch[1] = __builtin_amdgcn_mfma_f32_16x16x32_bf16(w1, b, Ch[1], 0, 0, 0);
      }
    }
    // epilogue: ht, state update, fused NEXT-step decay
#pragma unroll
    for (int mt = 0; mt < 2; ++mt) {
      float hn[4];
#pragma unroll
      for (int r = 0; r < 4; ++r) {
        float p = Ch[mt][r] + bf2f(us4_get(uh[mt], r));
        float e = __expf(2.f * p);
        float th = 1.f - 2.f / (e + 1.f);
        hn[r] = (1.f - zk[mt][r]) * Hst[mt][r] + zk[mt][r] * th;
      }
      if (s < NSTEP - 1) {
        float Hn[4];
#pragma unroll
        for (int r = 0; r < 4; ++r) {
          float dh = __expf(-fmaxf(bf2f(us4_get(ug[mt], r)), 0.f));
          Hn[r] = hn[r] * dh;
          Hst[mt][r] = Hn[r];
        }
        uint2 hw;
        hw.x = cvt_pk_bf16(Hn[0], Hn[1]);
        hw.y = cvt_pk_bf16(Hn[2], Hn[3]);
        *(uint2*)((char*)hb + col * 512 + (((joff0 + mt * 16) * 2) ^ hsw)) = hw;
      } else {
        float4 o4; o4.x = hn[0]; o4.y = hn[1]; o4.z = hn[2]; o4.w = hn[3];
        *(float4*)&hT[((size_t)bt * 16 + col) * 256 + joff0 + mt * 16] = o4;
      }
    }
    // prefetch uh for s+1, ug for s+2 (overshoot at s>=126 lands in Cin, unused)
#pragma unroll
    for (int mt = 0; mt < 2; ++mt) {
      uh[mt] = *(const ushort4*)(pnext + 512 + mt * 16);
      ug[mt] = *(const ushort4*)(pnext + SS + 768 + mt * 16);
    }
    pnext += SS;
    BSYNC();
  }
}

// ---------------------------------------------------------------------------
// bn_stats + fin
// ---------------------------------------------------------------------------
__global__ __launch_bounds__(256) void bn_stats(const float* __restrict__ hT,
                                                const float* __restrict__ gamma,
                                                const float* __restrict__ beta,
                                                const float* __restrict__ Wfc,
                                                const float* __restrict__ bfc,
                                                float* __restrict__ av) {
  int j = threadIdx.x;
  float sum = 0.f, sum2 = 0.f;
#pragma unroll 8
  for (int b = 0; b < NBAT; ++b) {
    float v = hT[(size_t)b * 256 + j];
    sum += v; sum2 += v * v;
  }
  float mu = sum * (1.f / NBAT);
  float var = sum2 * (1.f / NBAT) - mu * mu;
  float a = gamma[j] * Wfc[j] * rsqrtf(var + 1e-5f);
  av[j] = a;
  __shared__ float red[256];
  red[j] = beta[j] * Wfc[j] - a * mu;
  __syncthreads();
  for (int o = 128; o; o >>= 1) {
    if (j < o) red[j] += red[j + o];
    __syncthreads();
  }
  if (j == 0) av[256] = red[0] + bfc[0];
}

__global__ __launch_bounds__(64) void fin(const float* __restrict__ hT,
                                          const float* __restrict__ av,
                                          float* __restrict__ out) {
  int b = blockIdx.x, lane = threadIdx.x;
  float4 hv = *(const float4*)&hT[(size_t)b * 256 + lane * 4];
  float4 a  = *(const float4*)&av[lane * 4];
  float d = hv.x * a.x + hv.y * a.y + hv.z * a.z + hv.w * a.w;
  for (int o = 32; o; o >>= 1) d += __shfl_down(d, o);
  if (lane == 0) out[b] = d + av[256];
}

extern "C" void kernel_launch(void* const* d_in, const int* in_sizes, int n_in,
                              void* d_out, int out_size, void* d_ws, size_t ws_size,
                              hipStream_t stream) {
  (void)in_sizes; (void)n_in; (void)out_size; (void)ws_size;
  const float* X     = (const float*)d_in[0];
  const float* Xmean = (const float*)d_in[1];
  const float* Wz    = (const float*)d_in[2];
  const float* bz    = (const float*)d_in[3];
  const float* Wr    = (const float*)d_in[4];
  const float* br    = (const float*)d_in[5];
  const float* Wh    = (const float*)d_in[6];
  const float* bh    = (const float*)d_in[7];
  const float* Wgx   = (const float*)d_in[8];
  const float* bgx   = (const float*)d_in[9];
  const float* Wgh   = (const float*)d_in[10];
  const float* bgh   = (const float*)d_in[11];
  const float* gamma = (const float*)d_in[12];
  const float* beta  = (const float*)d_in[13];
  const float* Wfc   = (const float*)d_in[14];
  const float* bfc   = (const float*)d_in[15];
  float* out = (float*)d_out;
  char* ws = (char*)d_ws;

  unsigned short* Upre = (unsigned short*)(ws + 0ull);           // 134217728 B
  unsigned short* Cin  = (unsigned short*)(ws + 134217728ull);   // 50331648 B
  unsigned short* Wpre = (unsigned short*)(ws + 184549376ull);   // 786432 B
  unsigned short* Wzrh = (unsigned short*)(ws + 185335808ull);   // 262144 B
  unsigned short* WhhP = (unsigned short*)(ws + 185597952ull);   // 131072 B
  float*          Bpre = (float*)(ws + 185729024ull);            // 4096 B
  float*          hT   = (float*)(ws + 185733120ull);            // 524288 B
  float*          av   = (float*)(ws + 186257408ull);            // 2048 B
  float*          XmT  = (float*)(ws + 186259456ull);            // 65536 B

  pack_w<<<2372, 256, 0, stream>>>(Wz, Wr, Wh, Wgh, bz, br, bh, bgh, Xmean,
                                   Wpre, Wzrh, WhhP, Bpre, XmT);
  prep<<<1024, 128, 0, stream>>>(X, XmT, Wgx, bgx, Cin);
  u_gemm<<<1024, 256, 0, stream>>>(Cin, Wpre, Bpre, Upre);
  recur<<<32, 512, 0, stream>>>(Upre, Wzrh, WhhP, hT);
  bn_stats<<<1, 256, 0, stream>>>(hT, gamma, beta, Wfc, bfc, av);
  fin<<<512, 64, 0, stream>>>(hT, av, out);
}